// Round 1
// baseline (12522.990 us; speedup 1.0000x reference)
//
#include <hip/hip_runtime.h>
#include <hip/hip_bf16.h>
#include <stdint.h>
#include <math.h>

#define BATCH 256
#define SEQ   256
#define EMB   1024
#define HID   1024
#define NCLASS 32000
#define KTOT  2048   // EMB + HID

typedef __attribute__((ext_vector_type(8))) short bf16x8;   // 8 bf16 (4 VGPRs)
typedef __attribute__((ext_vector_type(4))) float f32x4;    // MFMA accumulator

// ---------- scalar helpers ----------
__device__ __forceinline__ unsigned short f2b(float f) {
  union { float f; unsigned u; } v; v.f = f;
  unsigned r = v.u + 0x7FFFu + ((v.u >> 16) & 1u);   // round-to-nearest-even
  return (unsigned short)(r >> 16);
}
__device__ __forceinline__ float b2f(unsigned short s) {
  union { unsigned u; float f; } v; v.u = ((unsigned)s) << 16;
  return v.f;
}
__device__ __forceinline__ void load_lds16(const void* g, void* l) {
  __builtin_amdgcn_global_load_lds(
      (const __attribute__((address_space(1))) unsigned int*)g,
      (__attribute__((address_space(3))) unsigned int*)l, 16, 0, 0);
}

// ---------- embedding lookup + bf16 cast:  Xt[t][b][k] = bf16(C[X[b][t]][k]) ----------
__global__ void embed_kernel(const int* __restrict__ X, const float* __restrict__ C,
                             unsigned short* __restrict__ Xt) {
  int n = blockIdx.x;             // n = t*BATCH + b
  int t = n >> 8, b = n & 255;
  int tok = X[(size_t)b * SEQ + t];
  float4 v = ((const float4*)(C + (size_t)tok * EMB))[threadIdx.x];
  ushort4 o;
  o.x = f2b(v.x); o.y = f2b(v.y); o.z = f2b(v.z); o.w = f2b(v.w);
  ((ushort4*)(Xt + (size_t)n * EMB))[threadIdx.x] = o;
}

// ---------- fp32 -> bf16 bulk cast ----------
__global__ void castf_kernel(const float* __restrict__ src, unsigned short* __restrict__ dst,
                             int n4) {
  int i = blockIdx.x * blockDim.x + threadIdx.x;
  if (i < n4) {
    float4 v = ((const float4*)src)[i];
    ushort4 o;
    o.x = f2b(v.x); o.y = f2b(v.y); o.z = f2b(v.z); o.w = f2b(v.w);
    ((ushort4*)dst)[i] = o;
  }
}

// ---------- one LSTM time step, both directions ----------
// Tile: M=128 batch rows x N=64 (4 gates x 16 hidden units), K=2048 ([x_t | h]).
// Grid: 2 Mtiles * 64 unit-tiles * 2 dirs = 256 WGs, 256 threads (4 waves, waves split M).
#define BM 128
#define BN 64
#define BK 64
__launch_bounds__(256)
__global__ void lstm_step_kernel(const unsigned short* __restrict__ Xt,
                                 const unsigned short* __restrict__ Wcat,
                                 const unsigned short* __restrict__ h_in,
                                 unsigned short* __restrict__ h_out,
                                 float* __restrict__ c_st,
                                 const float* __restrict__ b0, const float* __restrict__ b1,
                                 const float* __restrict__ b2, const float* __restrict__ b3,
                                 const float* __restrict__ b4, const float* __restrict__ b5,
                                 const float* __restrict__ b6, const float* __restrict__ b7,
                                 int t) {
  __shared__ unsigned short As[2][BM][BK];   // 2 x 16 KB
  __shared__ unsigned short Bs[2][BN][BK];   // 2 x  8 KB

  int bid = blockIdx.x;
  int d   = bid >> 7;            // direction
  int r   = bid & 127;
  int m0  = (r & 1) * BM;        // batch-tile base
  int j0  = (r >> 1) * 16;       // hidden-unit tile base
  int td  = d ? (SEQ - 1 - t) : t;
  int tid = threadIdx.x;

  const unsigned short* Asrc0 = Xt  + ((size_t)td * BATCH + m0) * EMB;  // x part (k<1024)
  const unsigned short* Asrc1 = h_in + ((size_t)d * BATCH + m0) * HID;  // h part (k>=1024)
  const unsigned short* Wd    = Wcat + (size_t)d * 4 * HID * KTOT;

  auto stageA = [&](int buf, int kb) {
    int kbase = kb * BK;
    const unsigned short* src; int ko;
    if (kbase < EMB) { src = Asrc0; ko = kbase; } else { src = Asrc1; ko = kbase - EMB; }
#pragma unroll
    for (int ri = 0; ri < 4; ++ri) {
      int slot = ri * 256 + tid;        // 1024 slots of 16B
      int row = slot >> 3;
      int ce  = (slot & 7) * 8;
      load_lds16(src + (size_t)row * 1024 + ko + ce, &As[buf][row][ce]);
    }
  };
  auto stageB = [&](int buf, int kb) {
    int kbase = kb * BK;
#pragma unroll
    for (int ri = 0; ri < 2; ++ri) {
      int slot = ri * 256 + tid;        // 512 slots
      int rr  = slot >> 3;              // 0..63 : rr = gate*16 + jj
      int g8  = rr >> 4;
      int jj  = rr & 15;
      int ce  = (slot & 7) * 8;
      load_lds16(Wd + (size_t)(g8 * HID + j0 + jj) * KTOT + kbase + ce, &Bs[buf][rr][ce]);
    }
  };

  int w = tid >> 6, lane = tid & 63;
  int lm = lane & 15, lq = lane >> 4;

  f32x4 zero = {0.f, 0.f, 0.f, 0.f};
  f32x4 acc[2][4];
#pragma unroll
  for (int mi = 0; mi < 2; ++mi)
#pragma unroll
    for (int g8 = 0; g8 < 4; ++g8) acc[mi][g8] = zero;

  stageA(0, 0); stageB(0, 0);
  for (int kb = 0; kb < KTOT / BK; ++kb) {
    int cur = kb & 1;
    __syncthreads();                         // drains vmcnt(0): buf[cur] ready
    if (kb + 1 < KTOT / BK) { stageA(1 - cur, kb + 1); stageB(1 - cur, kb + 1); }
#pragma unroll
    for (int kc = 0; kc < 2; ++kc) {
      bf16x8 a0 = *(const bf16x8*)&As[cur][w * 32 +  0 + lm][kc * 32 + lq * 8];
      bf16x8 a1 = *(const bf16x8*)&As[cur][w * 32 + 16 + lm][kc * 32 + lq * 8];
#pragma unroll
      for (int g8 = 0; g8 < 4; ++g8) {
        bf16x8 bb = *(const bf16x8*)&Bs[cur][g8 * 16 + lm][kc * 32 + lq * 8];
        acc[0][g8] = __builtin_amdgcn_mfma_f32_16x16x32_bf16(a0, bb, acc[0][g8], 0, 0, 0);
        acc[1][g8] = __builtin_amdgcn_mfma_f32_16x16x32_bf16(a1, bb, acc[1][g8], 0, 0, 0);
      }
    }
  }

  // epilogue: each lane owns all 4 gates of unit j = j0+lm for 8 batch rows
  const float* bi = d ? b4 : b0;
  const float* bf = d ? b5 : b1;
  const float* bo = d ? b6 : b2;
  const float* bgp= d ? b7 : b3;
  int j = j0 + lm;
  float vbi = bi[j], vbf = bf[j], vbo = bo[j], vbg = bgp[j];
#pragma unroll
  for (int mi = 0; mi < 2; ++mi) {
#pragma unroll
    for (int reg = 0; reg < 4; ++reg) {
      int b = m0 + w * 32 + mi * 16 + lq * 4 + reg;   // C/D row = quad*4 + reg
      float pi = acc[mi][0][reg] + vbi;
      float pf = acc[mi][1][reg] + vbf;
      float po = acc[mi][2][reg] + vbo;
      float pg = acc[mi][3][reg] + vbg;
      float ig = 1.f / (1.f + __expf(-pi));
      float fg = 1.f / (1.f + __expf(-pf));
      float og = 1.f / (1.f + __expf(-po));
      float gg = tanhf(pg);
      size_t ci = ((size_t)d * BATCH + b) * HID + j;
      float cn = fg * c_st[ci] + ig * gg;
      c_st[ci] = cn;
      h_out[ci] = f2b(og * tanhf(cn));
    }
  }
}

// ---------- hsum = bf16(h1 + h2) ----------
__global__ void hsum_kernel(const unsigned short* __restrict__ hfin,
                            unsigned short* __restrict__ hs) {
  int i = blockIdx.x * 256 + threadIdx.x;       // 65536 threads x 4 elems
  ushort4 a = ((const ushort4*)hfin)[i];
  ushort4 b = ((const ushort4*)(hfin + (size_t)BATCH * HID))[i];
  ushort4 o;
  o.x = f2b(b2f(a.x) + b2f(b.x));
  o.y = f2b(b2f(a.y) + b2f(b.y));
  o.z = f2b(b2f(a.z) + b2f(b.z));
  o.w = f2b(b2f(a.w) + b2f(b.w));
  ((ushort4*)hs)[i] = o;
}

// ---------- output GEMM: out[b][n] = hsum[b] . Wout[n] + b_out[n] ----------
// 128x128 tile, BK=64, 4 waves in 2x2, each wave 64x64 (m97 structure).
__launch_bounds__(256)
__global__ void out_gemm_kernel(const unsigned short* __restrict__ A,   // [256][1024]
                                const unsigned short* __restrict__ B,   // [32000][1024]
                                const float* __restrict__ bias,
                                float* __restrict__ Cout) {
  __shared__ unsigned short As[2][128][64];
  __shared__ unsigned short Bs[2][128][64];
  int bid = blockIdx.x;                 // 2 Mtiles x 250 Ntiles
  int m0 = (bid & 1) * 128;
  int n0 = (bid >> 1) * 128;
  int tid = threadIdx.x;

  auto stage = [&](int buf, int kb) {
    int kbase = kb * 64;
#pragma unroll
    for (int ri = 0; ri < 4; ++ri) {
      int slot = ri * 256 + tid;
      int row = slot >> 3;
      int ce  = (slot & 7) * 8;
      load_lds16(A + ((size_t)(m0 + row)) * HID + kbase + ce, &As[buf][row][ce]);
    }
#pragma unroll
    for (int ri = 0; ri < 4; ++ri) {
      int slot = ri * 256 + tid;
      int row = slot >> 3;
      int ce  = (slot & 7) * 8;
      load_lds16(B + ((size_t)(n0 + row)) * HID + kbase + ce, &Bs[buf][row][ce]);
    }
  };

  int w = tid >> 6, lane = tid & 63;
  int lm = lane & 15, lq = lane >> 4;
  int wm = w & 1, wn = w >> 1;

  f32x4 zero = {0.f, 0.f, 0.f, 0.f};
  f32x4 acc[4][4];
#pragma unroll
  for (int mi = 0; mi < 4; ++mi)
#pragma unroll
    for (int ni = 0; ni < 4; ++ni) acc[mi][ni] = zero;

  stage(0, 0);
  for (int kb = 0; kb < 16; ++kb) {
    int cur = kb & 1;
    __syncthreads();
    if (kb + 1 < 16) stage(1 - cur, kb + 1);
#pragma unroll
    for (int kc = 0; kc < 2; ++kc) {
      bf16x8 af[4];
#pragma unroll
      for (int mi = 0; mi < 4; ++mi)
        af[mi] = *(const bf16x8*)&As[cur][wm * 64 + mi * 16 + lm][kc * 32 + lq * 8];
#pragma unroll
      for (int ni = 0; ni < 4; ++ni) {
        bf16x8 bb = *(const bf16x8*)&Bs[cur][wn * 64 + ni * 16 + lm][kc * 32 + lq * 8];
#pragma unroll
        for (int mi = 0; mi < 4; ++mi)
          acc[mi][ni] = __builtin_amdgcn_mfma_f32_16x16x32_bf16(af[mi], bb, acc[mi][ni], 0, 0, 0);
      }
    }
  }

#pragma unroll
  for (int ni = 0; ni < 4; ++ni) {
    int n = n0 + wn * 64 + ni * 16 + lm;
    float bn = bias[n];
#pragma unroll
    for (int mi = 0; mi < 4; ++mi) {
#pragma unroll
      for (int reg = 0; reg < 4; ++reg) {
        int m = m0 + wm * 64 + mi * 16 + lq * 4 + reg;
        Cout[(size_t)m * NCLASS + n] = acc[mi][ni][reg] + bn;
      }
    }
  }
}

// ---------- host launcher ----------
extern "C" void kernel_launch(void* const* d_in, const int* in_sizes, int n_in,
                              void* d_out, int out_size, void* d_ws, size_t ws_size,
                              hipStream_t stream) {
  const int*   X    = (const int*)d_in[0];
  const float* C    = (const float*)d_in[1];
  const float* Wg[8];
  for (int i = 0; i < 8; ++i) Wg[i] = (const float*)d_in[2 + i];
  const float* bg[8];
  for (int i = 0; i < 8; ++i) bg[i] = (const float*)d_in[10 + i];
  const float* Wout = (const float*)d_in[18];
  const float* bout = (const float*)d_in[19];
  float* out = (float*)d_out;

  // workspace carve (total ~238 MB)
  uint8_t* p = (uint8_t*)d_ws;
  unsigned short* Xt   = (unsigned short*)p; p += (size_t)SEQ * BATCH * EMB * 2;  // 134.2 MB
  unsigned short* Wcat = (unsigned short*)p; p += (size_t)8 * HID * KTOT * 2;     //  33.6 MB
  unsigned short* Wob  = (unsigned short*)p; p += (size_t)NCLASS * HID * 2;       //  65.5 MB
  unsigned short* hb0  = (unsigned short*)p; p += (size_t)2 * BATCH * HID * 2;    //   1  MB
  unsigned short* hb1  = (unsigned short*)p; p += (size_t)2 * BATCH * HID * 2;    //   1  MB
  float*          cst  = (float*)p;          p += (size_t)2 * BATCH * HID * 4;    //   2  MB
  unsigned short* hs   = (unsigned short*)p; p += (size_t)BATCH * HID * 2;        // 0.5 MB

  hipMemsetAsync(hb0, 0, (size_t)2 * BATCH * HID * 2, stream);   // h(-1) = 0
  hipMemsetAsync(cst, 0, (size_t)2 * BATCH * HID * 4, stream);   // c(-1) = 0

  embed_kernel<<<SEQ * BATCH, 256, 0, stream>>>(X, C, Xt);
  for (int i = 0; i < 8; ++i)
    castf_kernel<<<2048, 256, 0, stream>>>(Wg[i], Wcat + (size_t)i * HID * KTOT,
                                           (HID * KTOT) / 4);
  castf_kernel<<<32000, 256, 0, stream>>>(Wout, Wob, (NCLASS * HID) / 4);

  unsigned short* hbuf[2] = {hb0, hb1};
  for (int t = 0; t < SEQ; ++t) {
    lstm_step_kernel<<<256, 256, 0, stream>>>(
        Xt, Wcat, hbuf[t & 1], hbuf[(t + 1) & 1], cst,
        bg[0], bg[1], bg[2], bg[3], bg[4], bg[5], bg[6], bg[7], t);
  }
  // final h is in hbuf[0] after 256 steps
  hsum_kernel<<<256, 256, 0, stream>>>(hb0, hs);
  out_gemm_kernel<<<500, 256, 0, stream>>>(hs, Wob, bout, out);
}

// Round 2
// 10507.011 us; speedup vs baseline: 1.1919x; 1.1919x over previous
//
#include <hip/hip_runtime.h>
#include <hip/hip_bf16.h>
#include <stdint.h>
#include <math.h>

#define BATCH 256
#define SEQ   256
#define EMB   1024
#define HID   1024
#define NCLASS 32000
#define KTOT  2048   // EMB + HID
#define NGATE 8192   // 2 dirs * 4 gates * HID

typedef __attribute__((ext_vector_type(8))) short bf16x8;   // 8 bf16 (4 VGPRs)
typedef __attribute__((ext_vector_type(4))) float f32x4;    // MFMA accumulator

// ---------- scalar helpers ----------
__device__ __forceinline__ unsigned short f2b(float f) {
  union { float f; unsigned u; } v; v.f = f;
  unsigned r = v.u + 0x7FFFu + ((v.u >> 16) & 1u);   // round-to-nearest-even
  return (unsigned short)(r >> 16);
}
__device__ __forceinline__ float b2f(unsigned short s) {
  union { unsigned u; float f; } v; v.u = ((unsigned)s) << 16;
  return v.f;
}
__device__ __forceinline__ void load_lds16(const void* g, void* l) {
  __builtin_amdgcn_global_load_lds(
      (const __attribute__((address_space(1))) unsigned int*)g,
      (__attribute__((address_space(3))) unsigned int*)l, 16, 0, 0);
}

// ---------- embedding lookup + bf16 cast:  Xt[t*B+b][k] = bf16(C[X[b][t]][k]) ----------
__global__ void embed_kernel(const int* __restrict__ X, const float* __restrict__ C,
                             unsigned short* __restrict__ Xt) {
  int n = blockIdx.x;             // n = t*BATCH + b
  int t = n >> 8, b = n & 255;
  int tok = X[(size_t)b * SEQ + t];
  float4 v = ((const float4*)(C + (size_t)tok * EMB))[threadIdx.x];
  ushort4 o;
  o.x = f2b(v.x); o.y = f2b(v.y); o.z = f2b(v.z); o.w = f2b(v.w);
  ((ushort4*)(Xt + (size_t)n * EMB))[threadIdx.x] = o;
}

// ---------- fp32 -> bf16 bulk cast ----------
__global__ void castf_kernel(const float* __restrict__ src, unsigned short* __restrict__ dst,
                             int n4) {
  int i = blockIdx.x * blockDim.x + threadIdx.x;
  if (i < n4) {
    float4 v = ((const float4*)src)[i];
    ushort4 o;
    o.x = f2b(v.x); o.y = f2b(v.y); o.z = f2b(v.z); o.w = f2b(v.w);
    ((ushort4*)dst)[i] = o;
  }
}

// ---------- concatenated bias vector bcat[n], n = d*4096 + gate*1024 + j ----------
__global__ void bcat_kernel(const float* b0, const float* b1, const float* b2,
                            const float* b3, const float* b4, const float* b5,
                            const float* b6, const float* b7, float* __restrict__ bcat) {
  int n = blockIdx.x * 256 + threadIdx.x;     // 8192
  const float* bp[8] = {b0, b1, b2, b3, b4, b5, b6, b7};
  bcat[n] = bp[n >> 10][n & 1023];
}

// ---------- Gx GEMM: Gx[m][n] = bf16( Xt[m] . Wcat[n][0:1024] + bcat[n] ) ----------
// M=65536 (t*B+b), N=8192, K=1024. 128x128 tile, BK=64, 4 waves 2x2.
__launch_bounds__(256)
__global__ void gx_gemm_kernel(const unsigned short* __restrict__ A,    // [65536][1024]
                               const unsigned short* __restrict__ Bw,   // Wcat [8192][2048]
                               const float* __restrict__ bcat,
                               unsigned short* __restrict__ Gx) {       // [65536][8192]
  __shared__ unsigned short As[2][128][64];
  __shared__ unsigned short Bs[2][128][64];
  int bid = blockIdx.x;                 // 512 Mtiles x 64 Ntiles, n inner
  int m0 = (bid >> 6) * 128;
  int n0 = (bid & 63) * 128;
  int tid = threadIdx.x;

  auto stage = [&](int buf, int kb) {
    int kbase = kb * 64;
#pragma unroll
    for (int ri = 0; ri < 4; ++ri) {
      int slot = ri * 256 + tid;
      int row = slot >> 3;
      int ce  = (slot & 7) * 8;
      load_lds16(A + (size_t)(m0 + row) * EMB + kbase + ce, &As[buf][row][ce]);
    }
#pragma unroll
    for (int ri = 0; ri < 4; ++ri) {
      int slot = ri * 256 + tid;
      int row = slot >> 3;
      int ce  = (slot & 7) * 8;
      load_lds16(Bw + (size_t)(n0 + row) * KTOT + kbase + ce, &Bs[buf][row][ce]);
    }
  };

  int w = tid >> 6, lane = tid & 63;
  int lm = lane & 15, lq = lane >> 4;
  int wm = w & 1, wn = w >> 1;

  f32x4 zero = {0.f, 0.f, 0.f, 0.f};
  f32x4 acc[4][4];
#pragma unroll
  for (int mi = 0; mi < 4; ++mi)
#pragma unroll
    for (int ni = 0; ni < 4; ++ni) acc[mi][ni] = zero;

  stage(0, 0);
  for (int kb = 0; kb < 16; ++kb) {
    int cur = kb & 1;
    __syncthreads();
    if (kb + 1 < 16) stage(1 - cur, kb + 1);
#pragma unroll
    for (int kc = 0; kc < 2; ++kc) {
      bf16x8 af[4];
#pragma unroll
      for (int mi = 0; mi < 4; ++mi)
        af[mi] = *(const bf16x8*)&As[cur][wm * 64 + mi * 16 + lm][kc * 32 + lq * 8];
#pragma unroll
      for (int ni = 0; ni < 4; ++ni) {
        bf16x8 bb = *(const bf16x8*)&Bs[cur][wn * 64 + ni * 16 + lm][kc * 32 + lq * 8];
#pragma unroll
        for (int mi = 0; mi < 4; ++mi)
          acc[mi][ni] = __builtin_amdgcn_mfma_f32_16x16x32_bf16(af[mi], bb, acc[mi][ni], 0, 0, 0);
      }
    }
  }

#pragma unroll
  for (int ni = 0; ni < 4; ++ni) {
    int n = n0 + wn * 64 + ni * 16 + lm;
    float bn = bcat[n];
#pragma unroll
    for (int mi = 0; mi < 4; ++mi) {
#pragma unroll
      for (int reg = 0; reg < 4; ++reg) {
        int m = m0 + wm * 64 + mi * 16 + lq * 4 + reg;
        Gx[(size_t)m * NGATE + n] = f2b(acc[mi][ni][reg] + bn);
      }
    }
  }
}

// ---------- one LSTM time step, both directions ----------
// Gx mode: K=1024 (h only), acc += Gx (bias folded). Fallback: K=2048, + bias.
// Tile M=128 x N=64 (4 gates x 16 units); grid 256 WGs x 256 thr.
#define BM 128
#define BN 64
#define BK 64
__launch_bounds__(256)
__global__ void lstm_step_kernel(const unsigned short* __restrict__ Xt,
                                 const unsigned short* __restrict__ Wcat,
                                 const unsigned short* __restrict__ Gx,   // may be null
                                 const unsigned short* __restrict__ h_in,
                                 unsigned short* __restrict__ h_out,
                                 float* __restrict__ c_st,
                                 const float* __restrict__ b0, const float* __restrict__ b1,
                                 const float* __restrict__ b2, const float* __restrict__ b3,
                                 const float* __restrict__ b4, const float* __restrict__ b5,
                                 const float* __restrict__ b6, const float* __restrict__ b7,
                                 int t) {
  __shared__ unsigned short As[2][BM][BK];   // 2 x 16 KB
  __shared__ unsigned short Bs[2][BN][BK];   // 2 x  8 KB

  int bid = blockIdx.x;
  int d   = bid >> 7;            // direction
  int r   = bid & 127;
  int m0  = (r & 1) * BM;        // batch-tile base
  int j0  = (r >> 1) * 16;       // hidden-unit tile base
  int td  = d ? (SEQ - 1 - t) : t;
  int tid = threadIdx.x;

  bool useGx = (Gx != nullptr);
  int  kiters = useGx ? (HID / BK) : (KTOT / BK);
  int  koff   = useGx ? EMB : 0;            // weight-column offset

  const unsigned short* Asrc0 = Xt  + ((size_t)td * BATCH + m0) * EMB;  // x part
  const unsigned short* Asrc1 = h_in + ((size_t)d * BATCH + m0) * HID;  // h part
  const unsigned short* Wd    = Wcat + (size_t)d * 4 * HID * KTOT;

  auto stageA = [&](int buf, int kb) {
    int kbase = kb * BK;
    const unsigned short* src; int ko;
    if (useGx)            { src = Asrc1; ko = kbase; }
    else if (kbase < EMB) { src = Asrc0; ko = kbase; }
    else                  { src = Asrc1; ko = kbase - EMB; }
#pragma unroll
    for (int ri = 0; ri < 4; ++ri) {
      int slot = ri * 256 + tid;        // 1024 slots of 16B
      int row = slot >> 3;
      int ce  = (slot & 7) * 8;
      load_lds16(src + (size_t)row * 1024 + ko + ce, &As[buf][row][ce]);
    }
  };
  auto stageB = [&](int buf, int kb) {
    int kbase = koff + kb * BK;
#pragma unroll
    for (int ri = 0; ri < 2; ++ri) {
      int slot = ri * 256 + tid;        // 512 slots
      int rr  = slot >> 3;              // rr = gate*16 + jj
      int g8  = rr >> 4;
      int jj  = rr & 15;
      int ce  = (slot & 7) * 8;
      load_lds16(Wd + (size_t)(g8 * HID + j0 + jj) * KTOT + kbase + ce, &Bs[buf][rr][ce]);
    }
  };

  int w = tid >> 6, lane = tid & 63;
  int lm = lane & 15, lq = lane >> 4;

  f32x4 zero = {0.f, 0.f, 0.f, 0.f};
  f32x4 acc[2][4];
#pragma unroll
  for (int mi = 0; mi < 2; ++mi)
#pragma unroll
    for (int g8 = 0; g8 < 4; ++g8) acc[mi][g8] = zero;

  stageA(0, 0); stageB(0, 0);
  for (int kb = 0; kb < kiters; ++kb) {
    int cur = kb & 1;
    __syncthreads();
    if (kb + 1 < kiters) { stageA(1 - cur, kb + 1); stageB(1 - cur, kb + 1); }
#pragma unroll
    for (int kc = 0; kc < 2; ++kc) {
      bf16x8 a0 = *(const bf16x8*)&As[cur][w * 32 +  0 + lm][kc * 32 + lq * 8];
      bf16x8 a1 = *(const bf16x8*)&As[cur][w * 32 + 16 + lm][kc * 32 + lq * 8];
#pragma unroll
      for (int g8 = 0; g8 < 4; ++g8) {
        bf16x8 bb = *(const bf16x8*)&Bs[cur][g8 * 16 + lm][kc * 32 + lq * 8];
        acc[0][g8] = __builtin_amdgcn_mfma_f32_16x16x32_bf16(a0, bb, acc[0][g8], 0, 0, 0);
        acc[1][g8] = __builtin_amdgcn_mfma_f32_16x16x32_bf16(a1, bb, acc[1][g8], 0, 0, 0);
      }
    }
  }

  // epilogue: each lane owns all 4 gates of unit j = j0+lm for 8 batch rows
  const float* bi = d ? b4 : b0;
  const float* bf = d ? b5 : b1;
  const float* bo = d ? b6 : b2;
  const float* bgp= d ? b7 : b3;
  int j = j0 + lm;
  float vbi, vbf, vbo, vbg;
  if (!useGx) { vbi = bi[j]; vbf = bf[j]; vbo = bo[j]; vbg = bgp[j]; }
  else        { vbi = vbf = vbo = vbg = 0.f; }
  const unsigned short* gxb = nullptr;
  if (useGx)
    gxb = Gx + (size_t)td * BATCH * NGATE + (size_t)d * 4096 + j0 + lm;

#pragma unroll
  for (int mi = 0; mi < 2; ++mi) {
#pragma unroll
    for (int reg = 0; reg < 4; ++reg) {
      int b = m0 + w * 32 + mi * 16 + lq * 4 + reg;   // C/D row = quad*4 + reg
      float pi = acc[mi][0][reg] + vbi;
      float pf = acc[mi][1][reg] + vbf;
      float po = acc[mi][2][reg] + vbo;
      float pg = acc[mi][3][reg] + vbg;
      if (useGx) {
        const unsigned short* g = gxb + (size_t)b * NGATE;
        pi += b2f(g[0]);
        pf += b2f(g[1024]);
        po += b2f(g[2048]);
        pg += b2f(g[3072]);
      }
      float ig = 1.f / (1.f + __expf(-pi));
      float fg = 1.f / (1.f + __expf(-pf));
      float og = 1.f / (1.f + __expf(-po));
      float gg = tanhf(pg);
      size_t ci = ((size_t)d * BATCH + b) * HID + j;
      float cn = fg * c_st[ci] + ig * gg;
      c_st[ci] = cn;
      h_out[ci] = f2b(og * tanhf(cn));
    }
  }
}

// ---------- hsum = bf16(h1 + h2) ----------
__global__ void hsum_kernel(const unsigned short* __restrict__ hfin,
                            unsigned short* __restrict__ hs) {
  int i = blockIdx.x * 256 + threadIdx.x;
  ushort4 a = ((const ushort4*)hfin)[i];
  ushort4 b = ((const ushort4*)(hfin + (size_t)BATCH * HID))[i];
  ushort4 o;
  o.x = f2b(b2f(a.x) + b2f(b.x));
  o.y = f2b(b2f(a.y) + b2f(b.y));
  o.z = f2b(b2f(a.z) + b2f(b.z));
  o.w = f2b(b2f(a.w) + b2f(b.w));
  ((ushort4*)hs)[i] = o;
}

// ---------- output GEMM: out[b][n] = hsum[b] . Wout[n] + b_out[n] ----------
__launch_bounds__(256)
__global__ void out_gemm_kernel(const unsigned short* __restrict__ A,   // [256][1024]
                                const unsigned short* __restrict__ B,   // [32000][1024]
                                const float* __restrict__ bias,
                                float* __restrict__ Cout) {
  __shared__ unsigned short As[2][128][64];
  __shared__ unsigned short Bs[2][128][64];
  int bid = blockIdx.x;                 // 2 Mtiles x 250 Ntiles
  int m0 = (bid & 1) * 128;
  int n0 = (bid >> 1) * 128;
  int tid = threadIdx.x;

  auto stage = [&](int buf, int kb) {
    int kbase = kb * 64;
#pragma unroll
    for (int ri = 0; ri < 4; ++ri) {
      int slot = ri * 256 + tid;
      int row = slot >> 3;
      int ce  = (slot & 7) * 8;
      load_lds16(A + ((size_t)(m0 + row)) * HID + kbase + ce, &As[buf][row][ce]);
    }
#pragma unroll
    for (int ri = 0; ri < 4; ++ri) {
      int slot = ri * 256 + tid;
      int row = slot >> 3;
      int ce  = (slot & 7) * 8;
      load_lds16(B + ((size_t)(n0 + row)) * HID + kbase + ce, &Bs[buf][row][ce]);
    }
  };

  int w = tid >> 6, lane = tid & 63;
  int lm = lane & 15, lq = lane >> 4;
  int wm = w & 1, wn = w >> 1;

  f32x4 zero = {0.f, 0.f, 0.f, 0.f};
  f32x4 acc[4][4];
#pragma unroll
  for (int mi = 0; mi < 4; ++mi)
#pragma unroll
    for (int ni = 0; ni < 4; ++ni) acc[mi][ni] = zero;

  stage(0, 0);
  for (int kb = 0; kb < 16; ++kb) {
    int cur = kb & 1;
    __syncthreads();
    if (kb + 1 < 16) stage(1 - cur, kb + 1);
#pragma unroll
    for (int kc = 0; kc < 2; ++kc) {
      bf16x8 af[4];
#pragma unroll
      for (int mi = 0; mi < 4; ++mi)
        af[mi] = *(const bf16x8*)&As[cur][wm * 64 + mi * 16 + lm][kc * 32 + lq * 8];
#pragma unroll
      for (int ni = 0; ni < 4; ++ni) {
        bf16x8 bb = *(const bf16x8*)&Bs[cur][wn * 64 + ni * 16 + lm][kc * 32 + lq * 8];
#pragma unroll
        for (int mi = 0; mi < 4; ++mi)
          acc[mi][ni] = __builtin_amdgcn_mfma_f32_16x16x32_bf16(af[mi], bb, acc[mi][ni], 0, 0, 0);
      }
    }
  }

#pragma unroll
  for (int ni = 0; ni < 4; ++ni) {
    int n = n0 + wn * 64 + ni * 16 + lm;
    float bn = bias[n];
#pragma unroll
    for (int mi = 0; mi < 4; ++mi) {
#pragma unroll
      for (int reg = 0; reg < 4; ++reg) {
        int m = m0 + wm * 64 + mi * 16 + lq * 4 + reg;
        Cout[(size_t)m * NCLASS + n] = acc[mi][ni][reg] + bn;
      }
    }
  }
}

// ---------- host launcher ----------
extern "C" void kernel_launch(void* const* d_in, const int* in_sizes, int n_in,
                              void* d_out, int out_size, void* d_ws, size_t ws_size,
                              hipStream_t stream) {
  const int*   X    = (const int*)d_in[0];
  const float* C    = (const float*)d_in[1];
  const float* Wg[8];
  for (int i = 0; i < 8; ++i) Wg[i] = (const float*)d_in[2 + i];
  const float* bg[8];
  for (int i = 0; i < 8; ++i) bg[i] = (const float*)d_in[10 + i];
  const float* Wout = (const float*)d_in[18];
  const float* bout = (const float*)d_in[19];
  float* out = (float*)d_out;

  // workspace carve
  const size_t szXt   = (size_t)SEQ * BATCH * EMB * 2;      // 134.2 MB
  const size_t szWcat = (size_t)8 * HID * KTOT * 2;         //  33.6 MB
  const size_t szWob  = (size_t)NCLASS * HID * 2;           //  65.5 MB
  const size_t szH    = (size_t)2 * BATCH * HID * 2;        //   1  MB
  const size_t szC    = (size_t)2 * BATCH * HID * 4;        //   2  MB
  const size_t szHs   = (size_t)BATCH * HID * 2;            // 0.5 MB
  const size_t szBc   = (size_t)NGATE * 4;                  //  32 KB
  const size_t szGx   = (size_t)SEQ * BATCH * NGATE * 2;    // 1.074 GB

  uint8_t* p = (uint8_t*)d_ws;
  unsigned short* Xt   = (unsigned short*)p; p += szXt;
  unsigned short* Wcat = (unsigned short*)p; p += szWcat;
  unsigned short* Wob  = (unsigned short*)p; p += szWob;
  unsigned short* hb0  = (unsigned short*)p; p += szH;
  unsigned short* hb1  = (unsigned short*)p; p += szH;
  float*          cst  = (float*)p;          p += szC;
  unsigned short* hs   = (unsigned short*)p; p += szHs;
  float*          bcat = (float*)p;          p += szBc;
  unsigned short* Gx   = (unsigned short*)p; p += szGx;

  size_t need_full = (size_t)(p - (uint8_t*)d_ws);
  bool useGx = (ws_size >= need_full);
  if (!useGx) Gx = nullptr;

  hipMemsetAsync(hb0, 0, szH, stream);   // h(-1) = 0
  hipMemsetAsync(cst, 0, szC, stream);   // c(-1) = 0

  embed_kernel<<<SEQ * BATCH, 256, 0, stream>>>(X, C, Xt);
  for (int i = 0; i < 8; ++i)
    castf_kernel<<<2048, 256, 0, stream>>>(Wg[i], Wcat + (size_t)i * HID * KTOT,
                                           (HID * KTOT) / 4);
  castf_kernel<<<32000, 256, 0, stream>>>(Wout, Wob, (NCLASS * HID) / 4);

  if (useGx) {
    bcat_kernel<<<NGATE / 256, 256, 0, stream>>>(bg[0], bg[1], bg[2], bg[3],
                                                 bg[4], bg[5], bg[6], bg[7], bcat);
    gx_gemm_kernel<<<512 * 64, 256, 0, stream>>>(Xt, Wcat, bcat, Gx);
  }

  unsigned short* hbuf[2] = {hb0, hb1};
  for (int t = 0; t < SEQ; ++t) {
    lstm_step_kernel<<<256, 256, 0, stream>>>(
        Xt, Wcat, Gx, hbuf[t & 1], hbuf[(t + 1) & 1], cst,
        bg[0], bg[1], bg[2], bg[3], bg[4], bg[5], bg[6], bg[7], t);
  }
  // final h is in hbuf[0] after 256 steps
  hsum_kernel<<<256, 256, 0, stream>>>(hb0, hs);
  out_gemm_kernel<<<500, 256, 0, stream>>>(hs, Wob, bout, out);
}